// Round 13
// baseline (103.940 us; speedup 1.0000x reference)
//
#include <hip/hip_runtime.h>
#include <hip/hip_bf16.h>
#include <stdint.h>

#define NB 64
#define NC 512
#define NHW 784
#define NK 49
#define KP 64
#define NR 32
#define NTASK 10

typedef short sh8 __attribute__((ext_vector_type(8)));
typedef float f32x4 __attribute__((ext_vector_type(4)));
typedef int v4i __attribute__((ext_vector_type(4)));

__device__ __forceinline__ float wave_sum(float v) {
#pragma unroll
  for (int o = 32; o; o >>= 1) v += __shfl_xor(v, o);
  return v;
}

__device__ __forceinline__ void task_decode(int s, int& ti, int& tj) {
  // upper-triangle enumeration: (0,0)(0,1)(0,2)(0,3)(1,1)(1,2)(1,3)(2,2)(2,3)(3,3)
  if (s < 4) { ti = 0; tj = s; }
  else if (s < 7) { ti = 1; tj = s - 3; }
  else if (s < 9) { ti = 2; tj = s - 5; }
  else { ti = 3; tj = 3; }
}

// ---------------- K1: pool — coalesced loads, atomic-free LDS scatter/gather ----------------
__global__ __launch_bounds__(256) void pool_kernel(const float* __restrict__ x,
                                                   __hip_bfloat16* __restrict__ xap,
                                                   float* __restrict__ wbuf,
                                                   float* __restrict__ gap) {
  __shared__ float sf[4][196];
  int t = threadIdx.x, wid = t >> 6, lane = t & 63;
  int row = blockIdx.x * 4 + wid;  // b*512 + c
  const f32x4* xr = (const f32x4*)(x + (size_t)row * NHW);
  f32x4 v0 = xr[lane];
  f32x4 v1 = xr[lane + 64];
  f32x4 v2 = xr[lane + 128];
  sf[wid][lane] = (v0.x + v0.y) + (v0.z + v0.w);
  sf[wid][lane + 64] = (v1.x + v1.y) + (v1.z + v1.w);
  sf[wid][lane + 128] = (v2.x + v2.y) + (v2.z + v2.w);
  if (lane < 4) {
    f32x4 v3 = xr[lane + 192];
    sf[wid][lane + 192] = (v3.x + v3.y) + (v3.z + v3.w);
  }
  __syncthreads();
  float bin = 0.f;
  if (lane < NK) {
    int pr = lane / 7, pc = lane - pr * 7;
    int f0 = pr * 28 + pc;
    bin = ((sf[wid][f0] + sf[wid][f0 + 7]) + (sf[wid][f0 + 14] + sf[wid][f0 + 21])) * 0.0625f;
  }
  float s1 = wave_sum(bin);
  float s2 = wave_sum(bin * bin);
  xap[(size_t)row * KP + lane] = __float2bfloat16(bin);  // lanes>=49 write 0 pad
  if (lane == 0) {
    wbuf[row] = sqrtf(s2);         // per-channel L2 norm (exact; once per row)
    gap[row] = s1 * (1.f / 49.f);  // == mean over 784
  }
}

// ============== K2: FUSED middle — one block per batch (1024 thr = 16 waves) ==============
// Stage whole-batch xap (64KB, swizzled) once -> z -> pass A (dsum) -> pass B (sim,
// tfull/S in LDS) -> MLP -> scl.  No intermediate global buffers, no cross-block deps.
__global__ __launch_bounds__(1024) void middle_kernel(
    const __hip_bfloat16* __restrict__ xap, const float* __restrict__ wbuf,
    const float* __restrict__ gap, const float* __restrict__ wD,
    const float* __restrict__ bD, const float* __restrict__ wU,
    const float* __restrict__ bU, float* __restrict__ scl) {
  __shared__ __align__(16) __hip_bfloat16 X[NC * KP];  // 64 KB
  __shared__ float wL[NC], zL[NC], tfull[NC], chL[NC];
  __shared__ float red[16];
  __shared__ float hL[NR];
  int b = blockIdx.x, t = threadIdx.x;
  int lane = t & 63, w = t >> 6;
  // ---- stage batch xap -> LDS (XOR-swizzled 16B chunks) ----
  const v4i* gx = (const v4i*)(xap + (size_t)b * NC * KP);
  v4i* lx = (v4i*)X;
#pragma unroll
  for (int q = 0; q < 4; ++q) {
    int cid = q * 1024 + t;  // 0..4095
    int r = cid >> 3, c = cid & 7;
    lx[(r << 3) | (c ^ (r & 7))] = gx[cid];
  }
  if (t < NC) {
    wL[t] = wbuf[b * NC + t];
    tfull[t] = 0.f;
  }
  // ---- z = (gap - mu)/std (unbiased); deterministic fixed-order red sums ----
  float g0 = (t < NC) ? gap[b * NC + t] : 0.f;
  float s1 = wave_sum(g0);
  if (lane == 0) red[w] = s1;
  __syncthreads();
  float mu = 0.f;
#pragma unroll
  for (int i = 0; i < 16; ++i) mu += red[i];
  mu *= (1.f / 512.f);
  float e0 = g0 - mu;
  float dd = (t < NC) ? e0 * e0 : 0.f;
  __syncthreads();
  float vv = wave_sum(dd);
  if (lane == 0) red[w] = vv;
  __syncthreads();
  float var = 0.f;
#pragma unroll
  for (int i = 0; i < 16; ++i) var += red[i];
  float inv_sd = __builtin_amdgcn_rsqf(var * (1.f / 511.f));
  if (t < NC) zL[t] = e0 * inv_sd;
  __syncthreads();  // X, wL, zL, tfull ready

  int wi = w >> 2, wn = w & 3;  // 4x4 wave grid: 32 rows x 32 cols per wave
  int l15 = lane & 15, g16 = lane >> 4;
  const v4i* lxc = (const v4i*)X;

  // ---- pass A: dsum over 10 triangle tiles (weighted) ----
  float dacc = 0.f;
#pragma unroll 1
  for (int s = 0; s < NTASK; ++s) {
    int ti, tj;
    task_decode(s, ti, tj);
    int i0 = ti * 128, j0 = tj * 128;
    sh8 af[2][2], bfr[2][2];
#pragma unroll
    for (int f = 0; f < 2; ++f)
#pragma unroll
      for (int ks = 0; ks < 2; ++ks) {
        int ra = i0 + wi * 32 + f * 16 + l15;
        int rb = j0 + wn * 32 + f * 16 + l15;
        int cg = ks * 4 + g16;
        af[f][ks] = __builtin_bit_cast(sh8, lxc[(ra << 3) | (cg ^ (ra & 7))]);
        bfr[f][ks] = __builtin_bit_cast(sh8, lxc[(rb << 3) | (cg ^ (rb & 7))]);
      }
    f32x4 acc[2][2];
#pragma unroll
    for (int fm = 0; fm < 2; ++fm)
#pragma unroll
      for (int fn = 0; fn < 2; ++fn) acc[fm][fn] = (f32x4){0.f, 0.f, 0.f, 0.f};
#pragma unroll
    for (int ks = 0; ks < 2; ++ks)
#pragma unroll
      for (int fm = 0; fm < 2; ++fm)
#pragma unroll
        for (int fn = 0; fn < 2; ++fn)
          acc[fm][fn] = __builtin_amdgcn_mfma_f32_16x16x32_bf16(af[fm][ks], bfr[fn][ks],
                                                                acc[fm][fn], 0, 0, 0);
    float a2[2][4], b2v[2];
#pragma unroll
    for (int fm = 0; fm < 2; ++fm)
#pragma unroll
      for (int rg = 0; rg < 4; ++rg) {
        float a = wL[i0 + wi * 32 + fm * 16 + g16 * 4 + rg];
        a2[fm][rg] = a * a;
      }
#pragma unroll
    for (int fn = 0; fn < 2; ++fn) {
      float ww = wL[j0 + wn * 32 + fn * 16 + l15];
      b2v[fn] = ww * ww;
    }
    float dsum = 0.f;
#pragma unroll
    for (int fm = 0; fm < 2; ++fm)
#pragma unroll
      for (int fn = 0; fn < 2; ++fn)
#pragma unroll
        for (int rg = 0; rg < 4; ++rg) {
          float d2 = fmaf(-2.f, acc[fm][fn][rg], a2[fm][rg] + b2v[fn]);
          dsum += __builtin_amdgcn_sqrtf(fmaxf(d2, 0.f));
        }
    dacc += dsum * ((ti == tj) ? 1.f : 2.f);
  }
  dacc = wave_sum(dacc);
  __syncthreads();  // red reuse guard
  if (lane == 0) red[w] = dacc;
  __syncthreads();
  float sD = 0.f;
#pragma unroll
  for (int i = 0; i < 16; ++i) sD += red[i];
  float nim = -1.44269504f / (sD * (1.f / 262144.f) + 1e-10f);  // -log2e/mean_d

  // ---- pass B: sim epilogue; tfull/S accumulated in LDS ----
  float ssacc = 0.f;
#pragma unroll 1
  for (int s = 0; s < NTASK; ++s) {
    int ti, tj;
    task_decode(s, ti, tj);
    bool diag = (ti == tj);
    int i0 = ti * 128, j0 = tj * 128;
    sh8 af[2][2], bfr[2][2];
#pragma unroll
    for (int f = 0; f < 2; ++f)
#pragma unroll
      for (int ks = 0; ks < 2; ++ks) {
        int ra = i0 + wi * 32 + f * 16 + l15;
        int rb = j0 + wn * 32 + f * 16 + l15;
        int cg = ks * 4 + g16;
        af[f][ks] = __builtin_bit_cast(sh8, lxc[(ra << 3) | (cg ^ (ra & 7))]);
        bfr[f][ks] = __builtin_bit_cast(sh8, lxc[(rb << 3) | (cg ^ (rb & 7))]);
      }
    f32x4 acc[2][2];
#pragma unroll
    for (int fm = 0; fm < 2; ++fm)
#pragma unroll
      for (int fn = 0; fn < 2; ++fn) acc[fm][fn] = (f32x4){0.f, 0.f, 0.f, 0.f};
#pragma unroll
    for (int ks = 0; ks < 2; ++ks)
#pragma unroll
      for (int fm = 0; fm < 2; ++fm)
#pragma unroll
        for (int fn = 0; fn < 2; ++fn)
          acc[fm][fn] = __builtin_amdgcn_mfma_f32_16x16x32_bf16(af[fm][ks], bfr[fn][ks],
                                                                acc[fm][fn], 0, 0, 0);
    float a2[2][4], ia[2][4], zi[2][4];
#pragma unroll
    for (int fm = 0; fm < 2; ++fm)
#pragma unroll
      for (int rg = 0; rg < 4; ++rg) {
        int il = wi * 32 + fm * 16 + g16 * 4 + rg;
        float a = wL[i0 + il];
        a2[fm][rg] = a * a;
        ia[fm][rg] = __builtin_amdgcn_rcpf(fmaxf(a, 1e-7f));
        zi[fm][rg] = zL[i0 + il];
      }
    float b2v[2], ib[2], zj[2];
#pragma unroll
    for (int fn = 0; fn < 2; ++fn) {
      int jl = wn * 32 + fn * 16 + l15;
      float ww = wL[j0 + jl];
      b2v[fn] = ww * ww;
      ib[fn] = __builtin_amdgcn_rcpf(fmaxf(ww, 1e-7f));
      zj[fn] = zL[j0 + jl];
    }
    float ssum = 0.f;
    float trow[2][4];
    float tcol[2] = {0.f, 0.f};
#pragma unroll
    for (int fm = 0; fm < 2; ++fm)
#pragma unroll
      for (int rg = 0; rg < 4; ++rg) trow[fm][rg] = 0.f;
#pragma unroll
    for (int fm = 0; fm < 2; ++fm)
#pragma unroll
      for (int fn = 0; fn < 2; ++fn) {
        float ibn = ib[fn];
#pragma unroll
        for (int rg = 0; rg < 4; ++rg) {
          float g = acc[fm][fn][rg];
          float d2 = fmaf(-2.f, g, a2[fm][rg] + b2v[fn]);
          float d = __builtin_amdgcn_sqrtf(fmaxf(d2, 0.f));
          float sim = fmaxf(g, 0.f) * ia[fm][rg] * ibn * exp2f(d * nim);
          if (diag) {
            int il = wi * 32 + fm * 16 + g16 * 4 + rg;
            int jl = wn * 32 + fn * 16 + l15;
            if (il == jl) sim = 0.f;
          }
          ssum += sim;
          trow[fm][rg] = fmaf(sim, zj[fn], trow[fm][rg]);
          tcol[fn] = fmaf(sim, zi[fm][rg], tcol[fn]);
        }
      }
#pragma unroll
    for (int fm = 0; fm < 2; ++fm)
#pragma unroll
      for (int rg = 0; rg < 4; ++rg) {
        float v = trow[fm][rg];
#pragma unroll
        for (int o = 8; o; o >>= 1) v += __shfl_xor(v, o);
        if (l15 == 0) atomicAdd(&tfull[i0 + wi * 32 + fm * 16 + g16 * 4 + rg], v);
      }
    if (!diag) {
#pragma unroll
      for (int fn = 0; fn < 2; ++fn) {
        float v = tcol[fn];
        v += __shfl_xor(v, 16);
        v += __shfl_xor(v, 32);
        if (g16 == 0) atomicAdd(&tfull[j0 + wn * 32 + fn * 16 + l15], v);
      }
    }
    ssacc += ssum * (diag ? 1.f : 2.f);
  }
  ssacc = wave_sum(ssacc);
  __syncthreads();  // red reuse + tfull completion
  if (lane == 0) red[w] = ssacc;
  __syncthreads();
  float S = 0.f;
#pragma unroll
  for (int i = 0; i < 16; ++i) S += red[i];
  float invS = 1.f / (S + 1e-10f);

  // ---- MLP: local_mi -> normalize -> 512->32 relu -> 32->512 sigmoid ----
  float lm = (t < NC) ? zL[t] * tfull[t] * invS : 0.f;
  float q3 = wave_sum(lm);
  __syncthreads();
  if (lane == 0) red[w] = q3;
  __syncthreads();
  float m_ = 0.f;
#pragma unroll
  for (int i = 0; i < 16; ++i) m_ += red[i];
  m_ *= (1.f / 512.f);
  float d0 = lm - m_;
  float dd2 = (t < NC) ? d0 * d0 : 0.f;
  float vv2 = wave_sum(dd2);
  __syncthreads();
  if (lane == 0) red[w] = vv2;
  __syncthreads();
  float v2s = 0.f;
#pragma unroll
  for (int i = 0; i < 16; ++i) v2s += red[i];
  float isd2 = __builtin_amdgcn_rcpf(sqrtf(v2s * (1.f / 511.f)) + 1e-12f);
  if (t < NC) chL[t] = d0 * isd2;
  __syncthreads();
  int k = t >> 5, p = t & 31;  // 32 rows x 32 threads
  const float* wrow = wD + k * NC + p * 16;
  const float* cp = chL + p * 16;
  float hp = 0.f;
#pragma unroll
  for (int i = 0; i < 16; ++i) hp += wrow[i] * cp[i];
#pragma unroll
  for (int o = 16; o; o >>= 1) hp += __shfl_xor(hp, o);
  if (p == 0) hL[k] = fmaxf(hp + bD[k], 0.f);
  __syncthreads();
  if (t < NC) {
    const float* wrU = wU + t * NR;
    float att = bU[t];
#pragma unroll
    for (int kk = 0; kk < NR; ++kk) att += hL[kk] * wrU[kk];
    scl[b * NC + t] = __builtin_amdgcn_rcpf(1.f + __expf(-att));
  }
}

// ---------------- K3: out = x * scale (x from L3; NT store for out) ----------------
__global__ __launch_bounds__(256) void scale_kernel(const float* __restrict__ x,
                                                    const float* __restrict__ scl,
                                                    float* __restrict__ out) {
  unsigned idx = blockIdx.x * 256u + threadIdx.x;  // float4 index, total 6422528
  unsigned row = idx / 196u;                       // b*512 + c
  float s = scl[row];
  f32x4 v = ((const f32x4*)x)[idx];
  v *= s;
  __builtin_nontemporal_store(v, ((f32x4*)out) + idx);
}

extern "C" void kernel_launch(void* const* d_in, const int* in_sizes, int n_in,
                              void* d_out, int out_size, void* d_ws, size_t ws_size,
                              hipStream_t stream) {
  const float* x = (const float*)d_in[0];
  const float* wD = (const float*)d_in[1];
  const float* bD = (const float*)d_in[2];
  const float* wU = (const float*)d_in[3];
  const float* bU = (const float*)d_in[4];
  float* out = (float*)d_out;
  char* ws = (char*)d_ws;

  __hip_bfloat16* xap = (__hip_bfloat16*)ws;  // 64*512*64*2 = 4 MB
  float* fbase = (float*)(ws + (size_t)NB * NC * KP * 2);
  float* wbuf = fbase;          // 32768 f32
  float* gap = wbuf + NB * NC;  // 32768
  float* scl = gap + NB * NC;   // 32768

  hipLaunchKernelGGL(pool_kernel, dim3(NB * NC / 4), dim3(256), 0, stream, x, xap, wbuf, gap);
  hipLaunchKernelGGL(middle_kernel, dim3(NB), dim3(1024), 0, stream, xap, wbuf, gap, wD, bD, wU,
                     bU, scl);
  hipLaunchKernelGGL(scale_kernel, dim3(25088), dim3(256), 0, stream, x, scl, out);
}

// Round 14
// 82.295 us; speedup vs baseline: 1.2630x; 1.2630x over previous
//
#include <hip/hip_runtime.h>
#include <hip/hip_bf16.h>
#include <stdint.h>

#define NB 64
#define NC 512
#define NHW 784
#define NK 49
#define KP 64
#define NR 32
#define NTASK 10

typedef short sh8 __attribute__((ext_vector_type(8)));
typedef float f32x4 __attribute__((ext_vector_type(4)));
typedef int v4i __attribute__((ext_vector_type(4)));

__device__ __forceinline__ float wave_sum(float v) {
#pragma unroll
  for (int o = 32; o; o >>= 1) v += __shfl_xor(v, o);
  return v;
}

__device__ __forceinline__ void task_decode(int s, int& ti, int& tj) {
  // upper-triangle enumeration: (0,0)(0,1)(0,2)(0,3)(1,1)(1,2)(1,3)(2,2)(2,3)(3,3)
  if (s < 4) { ti = 0; tj = s; }
  else if (s < 7) { ti = 1; tj = s - 3; }
  else if (s < 9) { ti = 2; tj = s - 5; }
  else { ti = 3; tj = 3; }
}

// ---------------- K1: pool — coalesced loads, atomic-free LDS scatter/gather ----------------
__global__ __launch_bounds__(256) void pool_kernel(const float* __restrict__ x,
                                                   __hip_bfloat16* __restrict__ xap,
                                                   float* __restrict__ wbuf,
                                                   float* __restrict__ gap) {
  __shared__ float sf[4][196];
  int t = threadIdx.x, wid = t >> 6, lane = t & 63;
  int row = blockIdx.x * 4 + wid;  // b*512 + c
  const f32x4* xr = (const f32x4*)(x + (size_t)row * NHW);
  f32x4 v0 = xr[lane];
  f32x4 v1 = xr[lane + 64];
  f32x4 v2 = xr[lane + 128];
  sf[wid][lane] = (v0.x + v0.y) + (v0.z + v0.w);
  sf[wid][lane + 64] = (v1.x + v1.y) + (v1.z + v1.w);
  sf[wid][lane + 128] = (v2.x + v2.y) + (v2.z + v2.w);
  if (lane < 4) {
    f32x4 v3 = xr[lane + 192];
    sf[wid][lane + 192] = (v3.x + v3.y) + (v3.z + v3.w);
  }
  __syncthreads();
  float bin = 0.f;
  if (lane < NK) {
    int pr = lane / 7, pc = lane - pr * 7;
    int f0 = pr * 28 + pc;
    bin = ((sf[wid][f0] + sf[wid][f0 + 7]) + (sf[wid][f0 + 14] + sf[wid][f0 + 21])) * 0.0625f;
  }
  float s1 = wave_sum(bin);
  float s2 = wave_sum(bin * bin);
  xap[(size_t)row * KP + lane] = __float2bfloat16(bin);  // lanes>=49 write 0 pad
  if (lane == 0) {
    wbuf[row] = sqrtf(s2);         // per-channel L2 norm (exact; once per row)
    gap[row] = s1 * (1.f / 49.f);  // == mean over 784
  }
}

// ---------------- K2: pass A — d-sums per triangle tile; s==0 block also emits z ----------
__global__ __launch_bounds__(256) void meand_kernel(const __hip_bfloat16* __restrict__ xap,
                                                    const float* __restrict__ wbuf,
                                                    const float* __restrict__ gap,
                                                    float* __restrict__ dpart,
                                                    float* __restrict__ zbuf) {
  __shared__ __align__(16) __hip_bfloat16 Ab[128 * KP];
  __shared__ __align__(16) __hip_bfloat16 Bb[128 * KP];
  __shared__ float wiL[128], wjL[128];
  __shared__ float red[4];
  int blk = blockIdx.x;
  int b = blk / NTASK, s = blk - b * NTASK;
  int ti, tj;
  task_decode(s, ti, tj);
  bool diag = (ti == tj);
  int i0 = ti * 128, j0 = tj * 128;
  int t = threadIdx.x;
  int lane = t & 63, wave = t >> 6;
  const v4i* ga = (const v4i*)(xap + ((size_t)b * NC + i0) * KP);
  const v4i* gb = (const v4i*)(xap + ((size_t)b * NC + j0) * KP);
  v4i* la = (v4i*)Ab;
  v4i* lb = (v4i*)Bb;
#pragma unroll
  for (int q = 0; q < 4; ++q) {
    int cid = q * 256 + t;
    int r = cid >> 3, c = cid & 7;
    int dst = (r << 3) | (c ^ (r & 7));
    la[dst] = ga[cid];
    lb[dst] = gb[cid];
  }
  if (t < 128) {
    wiL[t] = wbuf[b * NC + i0 + t];
    wjL[t] = wbuf[b * NC + j0 + t];
  }
  // one block per batch computes z = (gap - mu)/std (unbiased) -> zbuf (single source)
  if (s == 0) {
    float g0 = gap[b * NC + t], g1 = gap[b * NC + t + 256];
    float s1 = wave_sum(g0 + g1);
    if (lane == 0) red[wave] = s1;
    __syncthreads();
    float mu = ((red[0] + red[1]) + (red[2] + red[3])) * (1.f / 512.f);
    float e0 = g0 - mu, e1 = g1 - mu;
    __syncthreads();
    float vv = wave_sum(e0 * e0 + e1 * e1);
    if (lane == 0) red[wave] = vv;
    __syncthreads();
    float inv_sd = __builtin_amdgcn_rsqf(((red[0] + red[1]) + (red[2] + red[3])) * (1.f / 511.f));
    zbuf[b * NC + t] = e0 * inv_sd;
    zbuf[b * NC + t + 256] = e1 * inv_sd;
  }
  __syncthreads();
  int wi = wave >> 1, wn = wave & 1;
  int l15 = lane & 15, g16 = lane >> 4;
  sh8 af[4][2], bfr[4][2];
#pragma unroll
  for (int f = 0; f < 4; ++f) {
#pragma unroll
    for (int ks = 0; ks < 2; ++ks) {
      int ra = wi * 64 + f * 16 + l15;
      int rb = wn * 64 + f * 16 + l15;
      int cg2 = ks * 4 + g16;
      af[f][ks] = __builtin_bit_cast(sh8, ((const v4i*)Ab)[(ra << 3) | (cg2 ^ (ra & 7))]);
      bfr[f][ks] = __builtin_bit_cast(sh8, ((const v4i*)Bb)[(rb << 3) | (cg2 ^ (rb & 7))]);
    }
  }
  f32x4 acc[4][4];
#pragma unroll
  for (int fm = 0; fm < 4; ++fm)
#pragma unroll
    for (int fn = 0; fn < 4; ++fn) acc[fm][fn] = (f32x4){0.f, 0.f, 0.f, 0.f};
#pragma unroll
  for (int ks = 0; ks < 2; ++ks)
#pragma unroll
    for (int fm = 0; fm < 4; ++fm)
#pragma unroll
      for (int fn = 0; fn < 4; ++fn)
        acc[fm][fn] =
            __builtin_amdgcn_mfma_f32_16x16x32_bf16(af[fm][ks], bfr[fn][ks], acc[fm][fn], 0, 0, 0);
  float a2[4][4], b2[4];
#pragma unroll
  for (int fm = 0; fm < 4; ++fm)
#pragma unroll
    for (int rg = 0; rg < 4; ++rg) {
      float a = wiL[wi * 64 + fm * 16 + g16 * 4 + rg];
      a2[fm][rg] = a * a;
    }
#pragma unroll
  for (int fn = 0; fn < 4; ++fn) {
    float w = wjL[wn * 64 + fn * 16 + l15];
    b2[fn] = w * w;
  }
  float dsum = 0.f;
#pragma unroll
  for (int fm = 0; fm < 4; ++fm)
#pragma unroll
    for (int fn = 0; fn < 4; ++fn)
#pragma unroll
      for (int rg = 0; rg < 4; ++rg) {
        float d2 = fmaf(-2.f, acc[fm][fn][rg], a2[fm][rg] + b2[fn]);
        dsum += __builtin_amdgcn_sqrtf(fmaxf(d2, 0.f));  // HW sqrt (1 inst)
      }
  dsum = wave_sum(dsum);
  __syncthreads();  // red[] reuse guard (z phase)
  if (lane == 0) red[wave] = dsum;
  __syncthreads();
  if (t == 0) dpart[blk] = ((red[0] + red[1]) + (red[2] + red[3])) * (diag ? 1.f : 2.f);
}

// ---------------- K3: pass B — sim on triangle tiles; z from zbuf; single pre-MFMA sync ----
__global__ __launch_bounds__(256) void sim_kernel(const __hip_bfloat16* __restrict__ xap,
                                                  const float* __restrict__ wbuf,
                                                  const float* __restrict__ zbuf,
                                                  const float* __restrict__ dpart,
                                                  float* __restrict__ tpart,
                                                  float* __restrict__ spart) {
  __shared__ __align__(16) __hip_bfloat16 Ab[128 * KP];
  __shared__ __align__(16) __hip_bfloat16 Bb[128 * KP];
  __shared__ float wiL[128], wjL[128], zL[NC], tfull[NC];
  __shared__ float red[4];
  int blk = blockIdx.x;
  int b = blk / NTASK, s = blk - b * NTASK;
  int ti, tj;
  task_decode(s, ti, tj);
  bool diag = (ti == tj);
  int i0 = ti * 128, j0 = tj * 128;
  int t = threadIdx.x;
  int lane = t & 63, wave = t >> 6;
  float dsb = 0.f;
#pragma unroll
  for (int k = 0; k < NTASK; ++k) dsb += dpart[b * NTASK + k];
  float nim = -1.44269504f / (dsb * (1.f / 262144.f) + 1e-10f);  // -log2e/mean_d
  const v4i* ga = (const v4i*)(xap + ((size_t)b * NC + i0) * KP);
  const v4i* gb = (const v4i*)(xap + ((size_t)b * NC + j0) * KP);
  v4i* la = (v4i*)Ab;
  v4i* lb = (v4i*)Bb;
#pragma unroll
  for (int q = 0; q < 4; ++q) {
    int cid = q * 256 + t;
    int r = cid >> 3, c = cid & 7;
    int dst = (r << 3) | (c ^ (r & 7));
    la[dst] = ga[cid];
    lb[dst] = gb[cid];
  }
  if (t < 128) {
    wiL[t] = wbuf[b * NC + i0 + t];
    wjL[t] = wbuf[b * NC + j0 + t];
  }
  zL[t] = zbuf[b * NC + t];
  zL[t + 256] = zbuf[b * NC + t + 256];
  tfull[t] = 0.f;
  tfull[t + 256] = 0.f;
  __syncthreads();  // single pre-MFMA barrier
  int wi = wave >> 1, wn = wave & 1;
  int l15 = lane & 15, g16 = lane >> 4;
  sh8 af[4][2], bfr[4][2];
#pragma unroll
  for (int f = 0; f < 4; ++f) {
#pragma unroll
    for (int ks = 0; ks < 2; ++ks) {
      int ra = wi * 64 + f * 16 + l15;
      int rb = wn * 64 + f * 16 + l15;
      int cg2 = ks * 4 + g16;
      af[f][ks] = __builtin_bit_cast(sh8, ((const v4i*)Ab)[(ra << 3) | (cg2 ^ (ra & 7))]);
      bfr[f][ks] = __builtin_bit_cast(sh8, ((const v4i*)Bb)[(rb << 3) | (cg2 ^ (rb & 7))]);
    }
  }
  f32x4 acc[4][4];
#pragma unroll
  for (int fm = 0; fm < 4; ++fm)
#pragma unroll
    for (int fn = 0; fn < 4; ++fn) acc[fm][fn] = (f32x4){0.f, 0.f, 0.f, 0.f};
#pragma unroll
  for (int ks = 0; ks < 2; ++ks)
#pragma unroll
    for (int fm = 0; fm < 4; ++fm)
#pragma unroll
      for (int fn = 0; fn < 4; ++fn)
        acc[fm][fn] =
            __builtin_amdgcn_mfma_f32_16x16x32_bf16(af[fm][ks], bfr[fn][ks], acc[fm][fn], 0, 0, 0);
  float a2[4][4], ia[4][4], zi[4][4];
#pragma unroll
  for (int fm = 0; fm < 4; ++fm)
#pragma unroll
    for (int rg = 0; rg < 4; ++rg) {
      int il = wi * 64 + fm * 16 + g16 * 4 + rg;
      float a = wiL[il];
      a2[fm][rg] = a * a;
      ia[fm][rg] = __builtin_amdgcn_rcpf(fmaxf(a, 1e-7f));  // HW rcp
      zi[fm][rg] = zL[i0 + il];
    }
  float b2[4], ib[4], zj[4];
#pragma unroll
  for (int fn = 0; fn < 4; ++fn) {
    int jl = wn * 64 + fn * 16 + l15;
    float w = wjL[jl];
    b2[fn] = w * w;
    ib[fn] = __builtin_amdgcn_rcpf(fmaxf(w, 1e-7f));
    zj[fn] = zL[j0 + jl];
  }
  float ssum = 0.f;
  float trow[4][4];
  float tcol[4] = {0.f, 0.f, 0.f, 0.f};
#pragma unroll
  for (int fm = 0; fm < 4; ++fm)
#pragma unroll
    for (int rg = 0; rg < 4; ++rg) trow[fm][rg] = 0.f;
#pragma unroll
  for (int fm = 0; fm < 4; ++fm)
#pragma unroll
    for (int fn = 0; fn < 4; ++fn) {
      float ibn = ib[fn];
#pragma unroll
      for (int rg = 0; rg < 4; ++rg) {
        float g = acc[fm][fn][rg];
        float d2 = fmaf(-2.f, g, a2[fm][rg] + b2[fn]);
        float d = __builtin_amdgcn_sqrtf(fmaxf(d2, 0.f));
        float sim = fmaxf(g, 0.f) * ia[fm][rg] * ibn * exp2f(d * nim);
        if (diag) {
          int il = wi * 64 + fm * 16 + g16 * 4 + rg;
          int jl = wn * 64 + fn * 16 + l15;
          if (il == jl) sim = 0.f;
        }
        ssum += sim;
        trow[fm][rg] = fmaf(sim, zj[fn], trow[fm][rg]);
        tcol[fn] = fmaf(sim, zi[fm][rg], tcol[fn]);
      }
    }
  // row contributions: reduce over l15 (j within 16-group)
#pragma unroll
  for (int fm = 0; fm < 4; ++fm)
#pragma unroll
    for (int rg = 0; rg < 4; ++rg) {
      float v = trow[fm][rg];
#pragma unroll
      for (int o = 8; o; o >>= 1) v += __shfl_xor(v, o);
      if (l15 == 0) atomicAdd(&tfull[i0 + wi * 64 + fm * 16 + g16 * 4 + rg], v);
    }
  // column contributions (off-diag tiles only)
  if (!diag) {
#pragma unroll
    for (int fn = 0; fn < 4; ++fn) {
      float v = tcol[fn];
      v += __shfl_xor(v, 16);
      v += __shfl_xor(v, 32);
      if (g16 == 0) atomicAdd(&tfull[j0 + wn * 64 + fn * 16 + l15], v);
    }
  }
  ssum = wave_sum(ssum);
  if (lane == 0) red[wave] = ssum;
  __syncthreads();
  if (t == 0) spart[blk] = ((red[0] + red[1]) + (red[2] + red[3])) * (diag ? 1.f : 2.f);
  tpart[(size_t)blk * NC + t] = tfull[t];
  tpart[(size_t)blk * NC + t + 256] = tfull[t + 256];
}

// ---------------- K4: per-batch local_mi -> normalize -> MLP -> sigmoid scale ----------
__global__ __launch_bounds__(256) void mlp_kernel(const float* __restrict__ zbuf,
                                                  const float* __restrict__ tpart,
                                                  const float* __restrict__ spart,
                                                  const float* __restrict__ wD,
                                                  const float* __restrict__ bD,
                                                  const float* __restrict__ wU,
                                                  const float* __restrict__ bU,
                                                  float* __restrict__ scl) {
  __shared__ float red[4];
  __shared__ float chL[NC];
  __shared__ float hL[NR];
  int b = blockIdx.x, t = threadIdx.x;
  int lane = t & 63, wid = t >> 6;
  float S = 0.f;
#pragma unroll
  for (int k = 0; k < NTASK; ++k) S += spart[b * NTASK + k];
  float invS = 1.f / (S + 1e-10f);  // once
  float t0 = 0.f, t1 = 0.f;
#pragma unroll
  for (int j = 0; j < NTASK; ++j) {
    t0 += tpart[((size_t)b * NTASK + j) * NC + t];
    t1 += tpart[((size_t)b * NTASK + j) * NC + t + 256];
  }
  float lm0 = zbuf[b * NC + t] * t0 * invS;
  float lm1 = zbuf[b * NC + t + 256] * t1 * invS;
  float s2 = wave_sum(lm0 + lm1);
  if (lane == 0) red[wid] = s2;
  __syncthreads();
  float m = ((red[0] + red[1]) + (red[2] + red[3])) * (1.f / 512.f);
  float d0 = lm0 - m, d1 = lm1 - m;
  __syncthreads();
  float v2 = wave_sum(d0 * d0 + d1 * d1);
  if (lane == 0) red[wid] = v2;
  __syncthreads();
  float isd2 = __builtin_amdgcn_rcpf(
      sqrtf(((red[0] + red[1]) + (red[2] + red[3])) * (1.f / 511.f)) + 1e-12f);
  chL[t] = d0 * isd2;
  chL[t + 256] = d1 * isd2;
  __syncthreads();
  int k = t >> 3, p = t & 7;
  const float* wrow = wD + k * NC + p * 64;
  const float* cp = chL + p * 64;
  float hp = 0.f;
#pragma unroll
  for (int i = 0; i < 64; ++i) hp += wrow[i] * cp[i];
#pragma unroll
  for (int o = 4; o; o >>= 1) hp += __shfl_xor(hp, o);
  if (p == 0) hL[k] = fmaxf(hp + bD[k], 0.f);
  __syncthreads();
#pragma unroll
  for (int u = 0; u < 2; ++u) {
    int c = t + u * 256;
    const float* wrU = wU + c * NR;
    float att = bU[c];
#pragma unroll
    for (int kk = 0; kk < NR; ++kk) att += hL[kk] * wrU[kk];
    scl[b * NC + c] = __builtin_amdgcn_rcpf(1.f + __expf(-att));
  }
}

// ---------------- K5: out = x * scale (x from L3; NT store for out) ----------------
__global__ __launch_bounds__(256) void scale_kernel(const float* __restrict__ x,
                                                    const float* __restrict__ scl,
                                                    float* __restrict__ out) {
  unsigned idx = blockIdx.x * 256u + threadIdx.x;  // float4 index, total 6422528
  unsigned row = idx / 196u;                       // b*512 + c
  float s = scl[row];
  f32x4 v = ((const f32x4*)x)[idx];
  v *= s;
  __builtin_nontemporal_store(v, ((f32x4*)out) + idx);
}

extern "C" void kernel_launch(void* const* d_in, const int* in_sizes, int n_in,
                              void* d_out, int out_size, void* d_ws, size_t ws_size,
                              hipStream_t stream) {
  const float* x = (const float*)d_in[0];
  const float* wD = (const float*)d_in[1];
  const float* bD = (const float*)d_in[2];
  const float* wU = (const float*)d_in[3];
  const float* bU = (const float*)d_in[4];
  float* out = (float*)d_out;
  char* ws = (char*)d_ws;

  __hip_bfloat16* xap = (__hip_bfloat16*)ws;  // 64*512*64*2 = 4 MB
  float* fbase = (float*)(ws + (size_t)NB * NC * KP * 2);
  float* wbuf = fbase;                   // 32768 f32
  float* gap = wbuf + NB * NC;           // 32768
  float* dpart = gap + NB * NC;          // 640
  float* spart = dpart + NB * NTASK;     // 640
  float* tpart = spart + NB * NTASK;     // 64*10*512 = 327680
  float* scl = tpart + NB * NTASK * NC;  // 32768
  float* zbuf = scl + NB * NC;           // 32768

  hipLaunchKernelGGL(pool_kernel, dim3(NB * NC / 4), dim3(256), 0, stream, x, xap, wbuf, gap);
  hipLaunchKernelGGL(meand_kernel, dim3(NB * NTASK), dim3(256), 0, stream, xap, wbuf, gap, dpart,
                     zbuf);
  hipLaunchKernelGGL(sim_kernel, dim3(NB * NTASK), dim3(256), 0, stream, xap, wbuf, zbuf, dpart,
                     tpart, spart);
  hipLaunchKernelGGL(mlp_kernel, dim3(NB), dim3(256), 0, stream, zbuf, tpart, spart, wD, bD, wU,
                     bU, scl);
  hipLaunchKernelGGL(scale_kernel, dim3(25088), dim3(256), 0, stream, x, scl, out);
}